// Round 23
// baseline (255.277 us; speedup 1.0000x reference)
//
#include <hip/hip_runtime.h>
#include <hip/hip_bf16.h>
#include <cmath>

#define B_ 4
#define S_ 2048
#define D_ 1024
#define H_ 16
#define DH_ 64

typedef __bf16 bf16_t;
typedef __bf16 bf16x8 __attribute__((ext_vector_type(8)));
typedef __bf16 bf16x4 __attribute__((ext_vector_type(4)));
typedef float f32x4 __attribute__((ext_vector_type(4)));

static __device__ __forceinline__ f32x4 mfma16(bf16x8 a, bf16x8 b, f32x4 c) {
    return __builtin_amdgcn_mfma_f32_16x16x32_bf16(a, b, c, 0, 0, 0);
}

static __device__ __forceinline__ float fast_exp2(float x) {
#if __has_builtin(__builtin_amdgcn_exp2f)
    return __builtin_amdgcn_exp2f(x);
#else
    float r; asm("v_exp_f32 %0, %1" : "=v"(r) : "v"(x)); return r;
#endif
}

// async global->LDS, 16B per lane; lds dest wave-uniform (HW adds lane*16)
static __device__ __forceinline__ void glds16(const void* g, void* l) {
    __builtin_amdgcn_global_load_lds(
        (const __attribute__((address_space(1))) unsigned int*)g,
        (__attribute__((address_space(3))) unsigned int*)l, 16, 0, 0);
}

// ---------------- prep: RoPE table + W f32->bf16 ------------------------------------
__global__ __launch_bounds__(256)
void prep_kernel(const float* __restrict__ Wq, const float* __restrict__ Wk,
                 const float* __restrict__ Wv, const float* __restrict__ Wo,
                 bf16_t* __restrict__ Wb, float2* __restrict__ tab)
{
    int bid = blockIdx.x;
    if (bid < 256) {
        int idx = bid * 256 + threadIdx.x;          // 0 .. S_*32-1
        int s = idx >> 5, i = idx & 31;
        float inv = powf(10000.f, -(2.f * i) / 64.f);
        float ang = (float)s * inv;
        tab[idx] = make_float2(sinf(ang), cosf(ang));
    } else {
        int i = (bid - 256) * 256 + threadIdx.x;    // 0 .. 4*131072-1
        int t = i >> 17, j = i & 131071;
        const float* src = (t == 0) ? Wq : (t == 1) ? Wk : (t == 2) ? Wv : Wo;
        const float4* s = (const float4*)(src + (size_t)j * 8);
        float4 a = s[0], b = s[1];
        bf16x8 v = { (__bf16)a.x, (__bf16)a.y, (__bf16)a.z, (__bf16)a.w,
                     (__bf16)b.x, (__bf16)b.y, (__bf16)b.z, (__bf16)b.w };
        *(bf16x8*)(Wb + (size_t)i * 8) = v;
    }
}

// ---------------- Projection GEMM: 2-phase double-buffered --------------------------
// dst = X @ W^T. EPI 0: RoPE -> [B][H][S][DH]; EPI 1: V^T -> [B][H][DH][S].
template<int EPI>
__global__ __launch_bounds__(256)
void proj_kernel(const float* __restrict__ X, const bf16_t* __restrict__ W,
                 bf16_t* __restrict__ dst, const float2* __restrict__ tab)
{
    __shared__ bf16x8 lA[2][128 * 8];   // 32 KB
    __shared__ bf16x8 lB[2][128 * 8];   // 32 KB
    const int tid = threadIdx.x;
    const int gm0 = blockIdx.x * 128;
    const int gn0 = blockIdx.y * 128;
    const int wid = tid >> 6, lane = tid & 63;
    const int lr = lane & 15, lh = lane >> 4;
    const int wm = (wid >> 1) * 64, wn = (wid & 1) * 64;

    // this thread's 4 A-slots: LDS slot (row,s) holds k-chunk c = s^(row&7)
    int arow[4], aslot[4];
    const float* abase[4];
    #pragma unroll
    for (int i = 0; i < 4; ++i) {
        int slot = i * 256 + tid;
        int row = slot >> 3, s = slot & 7, c = s ^ (row & 7);
        arow[i] = row; aslot[i] = s;
        abase[i] = X + (size_t)(gm0 + row) * D_ + c * 8;
    }
    // B glds slot addresses (wave-cooperative)
    const bf16_t* bsrc[4]; int bbase[4];
    #pragma unroll
    for (int i = 0; i < 4; ++i) {
        int base = wid * 64 + i * 256;
        int slot = base + lane;
        int row = slot >> 3, s = slot & 7, c = s ^ (row & 7);
        bbase[i] = base;
        bsrc[i] = W + (size_t)(gn0 + row) * D_ + c * 8;   // + kt*64
    }

    // prologue: A0 regs -> lA[0]; B0 glds -> lB[0]
    float4 av0[4], av1[4];
    #pragma unroll
    for (int i = 0; i < 4; ++i) {
        av0[i] = *(const float4*)(abase[i]);
        av1[i] = *(const float4*)(abase[i] + 4);
    }
    #pragma unroll
    for (int i = 0; i < 4; ++i) glds16(bsrc[i], &lB[0][bbase[i]]);
    #pragma unroll
    for (int i = 0; i < 4; ++i) {
        lA[0][arow[i] * 8 + aslot[i]] = bf16x8{
            (__bf16)av0[i].x, (__bf16)av0[i].y, (__bf16)av0[i].z, (__bf16)av0[i].w,
            (__bf16)av1[i].x, (__bf16)av1[i].y, (__bf16)av1[i].z, (__bf16)av1[i].w };
    }
    __syncthreads();

    f32x4 acc[4][4] = {};
    int cur = 0;

    #pragma unroll 1
    for (int kt = 0; kt < D_ / 64; ++kt) {
        const int nxt = cur ^ 1;
        if (kt + 1 < D_ / 64) {
            #pragma unroll
            for (int i = 0; i < 4; ++i)
                glds16(bsrc[i] + (kt + 1) * 64, &lB[nxt][bbase[i]]);
            #pragma unroll
            for (int i = 0; i < 4; ++i) {
                av0[i] = *(const float4*)(abase[i] + (kt + 1) * 64);
                av1[i] = *(const float4*)(abase[i] + (kt + 1) * 64 + 4);
            }
        }
        #pragma unroll
        for (int ks = 0; ks < 2; ++ks) {
            bf16x8 af[4], bfr[4];
            int kh8 = ks * 4 + lh;
            #pragma unroll
            for (int mi = 0; mi < 4; ++mi) { int r = wm + mi * 16 + lr; af[mi]  = lA[cur][r * 8 + (kh8 ^ (r & 7))]; }
            #pragma unroll
            for (int ni = 0; ni < 4; ++ni) { int r = wn + ni * 16 + lr; bfr[ni] = lB[cur][r * 8 + (kh8 ^ (r & 7))]; }
            #pragma unroll
            for (int mi = 0; mi < 4; ++mi)
                #pragma unroll
                for (int ni = 0; ni < 4; ++ni)
                    acc[mi][ni] = mfma16(af[mi], bfr[ni], acc[mi][ni]);
        }
        if (kt + 1 < D_ / 64) {
            #pragma unroll
            for (int i = 0; i < 4; ++i) {    // f32-load wait hidden under MFMA above
                lA[nxt][arow[i] * 8 + aslot[i]] = bf16x8{
                    (__bf16)av0[i].x, (__bf16)av0[i].y, (__bf16)av0[i].z, (__bf16)av0[i].w,
                    (__bf16)av1[i].x, (__bf16)av1[i].y, (__bf16)av1[i].z, (__bf16)av1[i].w };
            }
        }
        __syncthreads();     // single barrier: drains B glds, publishes lA[nxt]
        cur = nxt;
    }

    // Epilogue. C/D layout: col = lane&15, row = (lane>>4)*4 + j
    #pragma unroll
    for (int mi = 0; mi < 4; ++mi) {
        #pragma unroll
        for (int j = 0; j < 4; ++j) {
            int m = gm0 + wm + mi * 16 + lh * 4 + j;   // b*S + s
            int b = m >> 11, s = m & (S_ - 1);
            #pragma unroll
            for (int ni = 0; ni < 4; ++ni) {
                int n = gn0 + wn + ni * 16 + lr;       // h*64 + dh
                int h = n >> 6, dh = n & 63;
                float x = acc[mi][ni][j];
                if (EPI == 0) {
                    float p = __shfl_xor(x, 1);        // partner column (adjacent lane)
                    float2 sc = tab[s * 32 + (dh >> 1)];
                    float r = (dh & 1) ? (p * sc.x + x * sc.y)
                                       : (x * sc.y - p * sc.x);
                    dst[(((size_t)b * H_ + h) * S_ + s) * DH_ + dh] = (bf16_t)r;
                } else {
                    dst[(((size_t)b * H_ + h) * DH_ + dh) * S_ + s] = (bf16_t)x;
                }
            }
        }
    }
}

// ---------------- Flash attention (causal), LPT + MFMA row-sum + V-from-L2 ----------
// 2048 blocks x 4 waves x 16 q-rows, largest-t first. Swapped QK^T, exp2 softmax,
// defer-max zero-cross-lane path, accL = P @ 1 on the matrix pipe. NEW: V^T read
// directly from global (L2-resident: 256 KB/bh shared by 32 same-XCD blocks) —
// removes lV staging (half the glds + drain mass), LDS 24->16 KB -> up to 8
// blocks/CU if VGPR stays <= 64 (launch_bounds kept at 6 to avoid forced spills).
__global__ __launch_bounds__(256, 6)
void attn_kernel(const bf16_t* __restrict__ qh, const bf16_t* __restrict__ kh,
                 const bf16_t* __restrict__ vT, bf16_t* __restrict__ O)
{
    __shared__ bf16x8 lK[64 * 8];      // [krow][dh-chunk], swizzled, 8 KB
    __shared__ bf16x8 lP8[4][128];     // per-wave P tile [16 q][64 kv], swizzled, 8 KB
    const int tid = threadIdx.x, wid = tid >> 6, lane = tid & 63;
    const int lr = lane & 15, lh = lane >> 4;
    const int bh = blockIdx.x & 63;          // bh%8 = xcd: q-slices of one bh share XCD
    const int t  = 31 - (blockIdx.x >> 6);   // 31..0, largest work first
    const bf16_t* Qp = qh + (size_t)bh * S_ * DH_;
    const bf16_t* Kp = kh + (size_t)bh * S_ * DH_;
    const bf16_t* Vp = vT + (size_t)bh * DH_ * S_;
    char* lP = (char*)lP8[wid];
    const int b = bh >> 4, h = bh & 15;
    const float QSCALE = 0.125f * 1.44269504f;   // 1/sqrt(DH) * log2(e)
    const int wq = t * 64 + wid * 16;
    const bf16x8 ones8 = { (__bf16)1.f, (__bf16)1.f, (__bf16)1.f, (__bf16)1.f,
                           (__bf16)1.f, (__bf16)1.f, (__bf16)1.f, (__bf16)1.f };

    // per-thread V fragment base: row dh = ni*16+lr, col lh*8 (+ ks*32 + kt*64)
    const bf16_t* vbase[4];
    #pragma unroll
    for (int ni = 0; ni < 4; ++ni)
        vbase[ni] = Vp + (size_t)(ni * 16 + lr) * S_ + lh * 8;

    // Q fragments (B-operand of S^T), pre-scaled into log2 domain
    bf16x8 qf[2];
    #pragma unroll
    for (int ks = 0; ks < 2; ++ks) {
        bf16x8 q8 = *(const bf16x8*)(Qp + (size_t)(wq + lr) * DH_ + ks * 32 + lh * 8);
        #pragma unroll
        for (int e = 0; e < 8; ++e) q8[e] = (__bf16)((float)q8[e] * QSCALE);
        qf[ks] = q8;
    }

    f32x4 accO[4] = {};
    f32x4 accL = {};                   // MFMA-accumulated row sums (all cols equal)
    float mrun = -1e30f;
    const int nkt = t + 1;

    #pragma unroll 1
    for (int kt = 0; kt < nkt; ++kt) {
        __syncthreads();
        #pragma unroll
        for (int i = 0; i < 2; ++i) {    // K staging only: 512 slots, 4 waves x 2 iters
            int base = i * 256 + (wid << 6);
            int slot = base + lane;
            int row = slot >> 3, s = slot & 7, c = s ^ (row & 7);
            glds16(Kp + (size_t)(kt * 64 + row) * DH_ + c * 8, &lK[base]);
        }
        __syncthreads();

        // S^T = K.Q^T : sc[kvi], kv row = 16*kvi + 4*lh + j, q col = lr
        f32x4 sc[4] = {};
        __builtin_amdgcn_s_setprio(1);
        #pragma unroll
        for (int ks = 0; ks < 2; ++ks) {
            int kh8 = ks * 4 + lh;
            #pragma unroll
            for (int kvi = 0; kvi < 4; ++kvi) {
                int r = kvi * 16 + lr;
                bf16x8 kf = lK[r * 8 + (kh8 ^ (r & 7))];
                sc[kvi] = mfma16(kf, qf[ks], sc[kvi]);
            }
        }
        __builtin_amdgcn_s_setprio(0);

        const int kvb = kt * 64 + 4 * lh;
        const int qg = wq + lr;
        float pv[16];
        if (kt == t) {                       // diagonal tile: causal mask (uniform branch)
            #pragma unroll
            for (int kvi = 0; kvi < 4; ++kvi)
                #pragma unroll
                for (int j = 0; j < 4; ++j) {
                    float x = sc[kvi][j];
                    if ((kvb + kvi * 16 + j) > qg) x = -1e30f;
                    pv[kvi * 4 + j] = x;
                }
        } else {
            #pragma unroll
            for (int kvi = 0; kvi < 4; ++kvi)
                #pragma unroll
                for (int j = 0; j < 4; ++j) pv[kvi * 4 + j] = sc[kvi][j];
        }

        // partial (per-lane) max via max3 triples: 8 ops
        float t0 = fmaxf(fmaxf(pv[0],  pv[1]),  pv[2]);
        float t1 = fmaxf(fmaxf(pv[3],  pv[4]),  pv[5]);
        float t2 = fmaxf(fmaxf(pv[6],  pv[7]),  pv[8]);
        float t3 = fmaxf(fmaxf(pv[9],  pv[10]), pv[11]);
        float t4 = fmaxf(fmaxf(pv[12], pv[13]), pv[14]);
        float u0 = fmaxf(fmaxf(t0, t1), t2);
        float u1 = fmaxf(fmaxf(t3, t4), pv[15]);
        float mxp = fmaxf(u0, u1);           // partial max (this lane only)

        float mnew = mrun;
        bool skip = __all(mxp <= mrun + 8.0f);   // defer-max: P bounded by 2^8
        if (!skip) {
            float mx = fmaxf(mxp, __shfl_xor(mxp, 16));   // full row max (rare path)
            mx = fmaxf(mx, __shfl_xor(mx, 32));
            mnew = fmaxf(mrun, mx);
            float rs = fast_exp2(mrun - mnew);
            mrun = mnew;
            #pragma unroll
            for (int j = 0; j < 4; ++j) {
                float rj = __shfl(rs, 4 * lh + j);
                #pragma unroll
                for (int ni = 0; ni < 4; ++ni) accO[ni][j] *= rj;
                accL[j] *= rj;
            }
        }
        // exp2 (no cross-lane, no explicit sum — MFMA handles it)
        #pragma unroll
        for (int i = 0; i < 16; ++i) pv[i] = fast_exp2(pv[i] - mnew);

        // write P[q][kv] to per-wave LDS: 8B per kvi, 16B-slot XOR swizzle
        #pragma unroll
        for (int kvi = 0; kvi < 4; ++kvi) {
            bf16x4 hv = { (__bf16)pv[kvi * 4 + 0], (__bf16)pv[kvi * 4 + 1],
                          (__bf16)pv[kvi * 4 + 2], (__bf16)pv[kvi * 4 + 3] };
            int slot = 2 * kvi + (lh >> 1);
            *(bf16x4*)(lP + lr * 128 + ((slot ^ (lr & 7)) * 16) + (lh & 1) * 8) = hv;
        }

        // PV: O += P @ V  and  L += P @ 1  (A = P from per-wave LDS, V from L2)
        __builtin_amdgcn_s_setprio(1);
        #pragma unroll
        for (int ks = 0; ks < 2; ++ks) {
            int slot = 4 * ks + lh;
            bf16x8 pf = *(const bf16x8*)(lP + lr * 128 + ((slot ^ (lr & 7)) * 16));
            #pragma unroll
            for (int ni = 0; ni < 4; ++ni) {
                bf16x8 vf = *(const bf16x8*)(vbase[ni] + kt * 64 + ks * 32);
                accO[ni] = mfma16(pf, vf, accO[ni]);
            }
            accL = mfma16(pf, ones8, accL);   // row sums (denominator), matrix pipe
        }
        __builtin_amdgcn_s_setprio(0);
    }

    // epilogue: rows q = 4*lh + j, col dh = ni*16 + lr; accL[j] = row sum (all lanes)
    #pragma unroll
    for (int j = 0; j < 4; ++j) {
        int s = wq + 4 * lh + j;
        float inv = 1.f / accL[j];
        #pragma unroll
        for (int ni = 0; ni < 4; ++ni) {
            int dh = ni * 16 + lr;
            O[((size_t)(b * S_ + s)) * D_ + h * DH_ + dh] = (bf16_t)(accO[ni][j] * inv);
        }
    }
}

// ---------------- Output GEMM: 2-phase double-buffered, glds both sides -------------
__global__ __launch_bounds__(256)
void out_kernel(const bf16_t* __restrict__ A, const bf16_t* __restrict__ W,
                float* __restrict__ out)
{
    __shared__ bf16x8 lA[2][128 * 8];   // 32 KB
    __shared__ bf16x8 lB[2][128 * 8];   // 32 KB
    const int tid = threadIdx.x;
    const int gm0 = blockIdx.x * 128;
    const int gn0 = blockIdx.y * 128;
    const int wid = tid >> 6, lane = tid & 63;
    const int lr = lane & 15, lh = lane >> 4;
    const int wm = (wid >> 1) * 64, wn = (wid & 1) * 64;

    const bf16_t* asrc[4]; const bf16_t* bsrc[4]; int sbase[4];
    #pragma unroll
    for (int i = 0; i < 4; ++i) {
        int base = wid * 64 + i * 256;
        int slot = base + lane;
        int row = slot >> 3, s = slot & 7, c = s ^ (row & 7);
        sbase[i] = base;
        asrc[i] = A + (size_t)(gm0 + row) * D_ + c * 8;
        bsrc[i] = W + (size_t)(gn0 + row) * D_ + c * 8;
    }

    // prologue: stage tile 0
    #pragma unroll
    for (int i = 0; i < 4; ++i) {
        glds16(asrc[i], &lA[0][sbase[i]]);
        glds16(bsrc[i], &lB[0][sbase[i]]);
    }
    __syncthreads();

    f32x4 acc[4][4] = {};
    int cur = 0;

    #pragma unroll 1
    for (int kt = 0; kt < D_ / 64; ++kt) {
        const int nxt = cur ^ 1;
        if (kt + 1 < D_ / 64) {
            #pragma unroll
            for (int i = 0; i < 4; ++i) {
                glds16(asrc[i] + (kt + 1) * 64, &lA[nxt][sbase[i]]);
                glds16(bsrc[i] + (kt + 1) * 64, &lB[nxt][sbase[i]]);
            }
        }
        #pragma unroll
        for (int ks = 0; ks < 2; ++ks) {
            bf16x8 af[4], bfr[4];
            int kh = ks * 4 + lh;
            #pragma unroll
            for (int mi = 0; mi < 4; ++mi) { int r = wm + mi * 16 + lr; af[mi]  = lA[cur][r * 8 + (kh ^ (r & 7))]; }
            #pragma unroll
            for (int ni = 0; ni < 4; ++ni) { int r = wn + ni * 16 + lr; bfr[ni] = lB[cur][r * 8 + (kh ^ (r & 7))]; }
            #pragma unroll
            for (int mi = 0; mi < 4; ++mi)
                #pragma unroll
                for (int ni = 0; ni < 4; ++ni)
                    acc[mi][ni] = mfma16(af[mi], bfr[ni], acc[mi][ni]);
        }
        __syncthreads();     // single barrier: drains next-tile glds
        cur = nxt;
    }

    #pragma unroll
    for (int mi = 0; mi < 4; ++mi)
        #pragma unroll
        for (int j = 0; j < 4; ++j) {
            int m = gm0 + wm + mi * 16 + lh * 4 + j;
            #pragma unroll
            for (int ni = 0; ni < 4; ++ni) {
                int n = gn0 + wn + ni * 16 + lr;
                out[(size_t)m * D_ + n] = acc[mi][ni][j];
            }
        }
}

extern "C" void kernel_launch(void* const* d_in, const int* in_sizes, int n_in,
                              void* d_out, int out_size, void* d_ws, size_t ws_size,
                              hipStream_t stream)
{
    const float* Q  = (const float*)d_in[0];
    const float* K  = (const float*)d_in[1];
    const float* V  = (const float*)d_in[2];
    const float* Wq = (const float*)d_in[3];
    const float* Wk = (const float*)d_in[4];
    const float* Wv = (const float*)d_in[5];
    const float* Wo = (const float*)d_in[6];
    float* out = (float*)d_out;

    char* ws = (char*)d_ws;
    const size_t MB = 1024 * 1024;
    bf16_t* qh  = (bf16_t*)(ws);                // [B][H][S][DH] bf16, 16 MB
    bf16_t* khb = (bf16_t*)(ws + 16 * MB);      // [B][H][S][DH] bf16, 16 MB
    bf16_t* vT  = (bf16_t*)(ws + 32 * MB);      // [B][H][DH][S] bf16, 16 MB
    bf16_t* Ob  = (bf16_t*)(ws + 48 * MB);      // [B*S][D] bf16, 16 MB
    bf16_t* Wb  = (bf16_t*)(ws + 64 * MB);      // 4 x [1024*1024] bf16, 8 MB
    float2* tab = (float2*)(ws + 72 * MB);      // [S][32] (sin,cos), 512 KB

    prep_kernel<<<2304, 256, 0, stream>>>(Wq, Wk, Wv, Wo, Wb, tab);

    dim3 g(64, 8);
    proj_kernel<0><<<g, 256, 0, stream>>>(Q, Wb + 0 * 1048576, qh, tab);
    proj_kernel<0><<<g, 256, 0, stream>>>(K, Wb + 1 * 1048576, khb, tab);
    proj_kernel<1><<<g, 256, 0, stream>>>(V, Wb + 2 * 1048576, vT, tab);

    attn_kernel<<<2048, 256, 0, stream>>>(qh, khb, vT, Ob);

    out_kernel<<<dim3(64, 8), 256, 0, stream>>>(Ob, Wb + 3 * 1048576, out);
}

// Round 24
// 174.208 us; speedup vs baseline: 1.4654x; 1.4654x over previous
//
#include <hip/hip_runtime.h>
#include <hip/hip_bf16.h>
#include <cmath>

#define B_ 4
#define S_ 2048
#define D_ 1024
#define H_ 16
#define DH_ 64

typedef __bf16 bf16_t;
typedef __bf16 bf16x8 __attribute__((ext_vector_type(8)));
typedef __bf16 bf16x4 __attribute__((ext_vector_type(4)));
typedef float f32x4 __attribute__((ext_vector_type(4)));

static __device__ __forceinline__ f32x4 mfma16(bf16x8 a, bf16x8 b, f32x4 c) {
    return __builtin_amdgcn_mfma_f32_16x16x32_bf16(a, b, c, 0, 0, 0);
}

static __device__ __forceinline__ float fast_exp2(float x) {
#if __has_builtin(__builtin_amdgcn_exp2f)
    return __builtin_amdgcn_exp2f(x);
#else
    float r; asm("v_exp_f32 %0, %1" : "=v"(r) : "v"(x)); return r;
#endif
}

// async global->LDS, 16B per lane; lds dest wave-uniform (HW adds lane*16)
static __device__ __forceinline__ void glds16(const void* g, void* l) {
    __builtin_amdgcn_global_load_lds(
        (const __attribute__((address_space(1))) unsigned int*)g,
        (__attribute__((address_space(3))) unsigned int*)l, 16, 0, 0);
}

// ---------------- prep: RoPE table + W f32->bf16 ------------------------------------
__global__ __launch_bounds__(256)
void prep_kernel(const float* __restrict__ Wq, const float* __restrict__ Wk,
                 const float* __restrict__ Wv, const float* __restrict__ Wo,
                 bf16_t* __restrict__ Wb, float2* __restrict__ tab)
{
    int bid = blockIdx.x;
    if (bid < 256) {
        int idx = bid * 256 + threadIdx.x;          // 0 .. S_*32-1
        int s = idx >> 5, i = idx & 31;
        float inv = powf(10000.f, -(2.f * i) / 64.f);
        float ang = (float)s * inv;
        tab[idx] = make_float2(sinf(ang), cosf(ang));
    } else {
        int i = (bid - 256) * 256 + threadIdx.x;    // 0 .. 4*131072-1
        int t = i >> 17, j = i & 131071;
        const float* src = (t == 0) ? Wq : (t == 1) ? Wk : (t == 2) ? Wv : Wo;
        const float4* s = (const float4*)(src + (size_t)j * 8);
        float4 a = s[0], b = s[1];
        bf16x8 v = { (__bf16)a.x, (__bf16)a.y, (__bf16)a.z, (__bf16)a.w,
                     (__bf16)b.x, (__bf16)b.y, (__bf16)b.z, (__bf16)b.w };
        *(bf16x8*)(Wb + (size_t)i * 8) = v;
    }
}

// ---------------- Projection GEMM: 2-phase double-buffered --------------------------
// dst = X @ W^T. EPI 0: RoPE -> [B][H][S][DH]; EPI 1: V^T -> [B][H][DH][S].
template<int EPI>
__global__ __launch_bounds__(256)
void proj_kernel(const float* __restrict__ X, const bf16_t* __restrict__ W,
                 bf16_t* __restrict__ dst, const float2* __restrict__ tab)
{
    __shared__ bf16x8 lA[2][128 * 8];   // 32 KB
    __shared__ bf16x8 lB[2][128 * 8];   // 32 KB
    const int tid = threadIdx.x;
    const int gm0 = blockIdx.x * 128;
    const int gn0 = blockIdx.y * 128;
    const int wid = tid >> 6, lane = tid & 63;
    const int lr = lane & 15, lh = lane >> 4;
    const int wm = (wid >> 1) * 64, wn = (wid & 1) * 64;

    // this thread's 4 A-slots: LDS slot (row,s) holds k-chunk c = s^(row&7)
    int arow[4], aslot[4];
    const float* abase[4];
    #pragma unroll
    for (int i = 0; i < 4; ++i) {
        int slot = i * 256 + tid;
        int row = slot >> 3, s = slot & 7, c = s ^ (row & 7);
        arow[i] = row; aslot[i] = s;
        abase[i] = X + (size_t)(gm0 + row) * D_ + c * 8;
    }
    // B glds slot addresses (wave-cooperative)
    const bf16_t* bsrc[4]; int bbase[4];
    #pragma unroll
    for (int i = 0; i < 4; ++i) {
        int base = wid * 64 + i * 256;
        int slot = base + lane;
        int row = slot >> 3, s = slot & 7, c = s ^ (row & 7);
        bbase[i] = base;
        bsrc[i] = W + (size_t)(gn0 + row) * D_ + c * 8;   // + kt*64
    }

    // prologue: A0 regs -> lA[0]; B0 glds -> lB[0]
    float4 av0[4], av1[4];
    #pragma unroll
    for (int i = 0; i < 4; ++i) {
        av0[i] = *(const float4*)(abase[i]);
        av1[i] = *(const float4*)(abase[i] + 4);
    }
    #pragma unroll
    for (int i = 0; i < 4; ++i) glds16(bsrc[i], &lB[0][bbase[i]]);
    #pragma unroll
    for (int i = 0; i < 4; ++i) {
        lA[0][arow[i] * 8 + aslot[i]] = bf16x8{
            (__bf16)av0[i].x, (__bf16)av0[i].y, (__bf16)av0[i].z, (__bf16)av0[i].w,
            (__bf16)av1[i].x, (__bf16)av1[i].y, (__bf16)av1[i].z, (__bf16)av1[i].w };
    }
    __syncthreads();

    f32x4 acc[4][4] = {};
    int cur = 0;

    #pragma unroll 1
    for (int kt = 0; kt < D_ / 64; ++kt) {
        const int nxt = cur ^ 1;
        if (kt + 1 < D_ / 64) {
            #pragma unroll
            for (int i = 0; i < 4; ++i)
                glds16(bsrc[i] + (kt + 1) * 64, &lB[nxt][bbase[i]]);
            #pragma unroll
            for (int i = 0; i < 4; ++i) {
                av0[i] = *(const float4*)(abase[i] + (kt + 1) * 64);
                av1[i] = *(const float4*)(abase[i] + (kt + 1) * 64 + 4);
            }
        }
        #pragma unroll
        for (int ks = 0; ks < 2; ++ks) {
            bf16x8 af[4], bfr[4];
            int kh8 = ks * 4 + lh;
            #pragma unroll
            for (int mi = 0; mi < 4; ++mi) { int r = wm + mi * 16 + lr; af[mi]  = lA[cur][r * 8 + (kh8 ^ (r & 7))]; }
            #pragma unroll
            for (int ni = 0; ni < 4; ++ni) { int r = wn + ni * 16 + lr; bfr[ni] = lB[cur][r * 8 + (kh8 ^ (r & 7))]; }
            #pragma unroll
            for (int mi = 0; mi < 4; ++mi)
                #pragma unroll
                for (int ni = 0; ni < 4; ++ni)
                    acc[mi][ni] = mfma16(af[mi], bfr[ni], acc[mi][ni]);
        }
        if (kt + 1 < D_ / 64) {
            #pragma unroll
            for (int i = 0; i < 4; ++i) {    // f32-load wait hidden under MFMA above
                lA[nxt][arow[i] * 8 + aslot[i]] = bf16x8{
                    (__bf16)av0[i].x, (__bf16)av0[i].y, (__bf16)av0[i].z, (__bf16)av0[i].w,
                    (__bf16)av1[i].x, (__bf16)av1[i].y, (__bf16)av1[i].z, (__bf16)av1[i].w };
            }
        }
        __syncthreads();     // single barrier: drains B glds, publishes lA[nxt]
        cur = nxt;
    }

    // Epilogue. C/D layout: col = lane&15, row = (lane>>4)*4 + j
    #pragma unroll
    for (int mi = 0; mi < 4; ++mi) {
        #pragma unroll
        for (int j = 0; j < 4; ++j) {
            int m = gm0 + wm + mi * 16 + lh * 4 + j;   // b*S + s
            int b = m >> 11, s = m & (S_ - 1);
            #pragma unroll
            for (int ni = 0; ni < 4; ++ni) {
                int n = gn0 + wn + ni * 16 + lr;       // h*64 + dh
                int h = n >> 6, dh = n & 63;
                float x = acc[mi][ni][j];
                if (EPI == 0) {
                    float p = __shfl_xor(x, 1);        // partner column (adjacent lane)
                    float2 sc = tab[s * 32 + (dh >> 1)];
                    float r = (dh & 1) ? (p * sc.x + x * sc.y)
                                       : (x * sc.y - p * sc.x);
                    dst[(((size_t)b * H_ + h) * S_ + s) * DH_ + dh] = (bf16_t)r;
                } else {
                    dst[(((size_t)b * H_ + h) * DH_ + dh) * S_ + s] = (bf16_t)x;
                }
            }
        }
    }
}

// ---------------- Flash attention (causal), LPT + MFMA row-sum ----------------------
// 2048 blocks x 4 waves x 16 q-rows, largest-t first. Swapped QK^T, exp2 softmax,
// defer-max zero-cross-lane path, 24 KB LDS, 2-barrier glds staging. Softmax
// denominator via MFMA with all-ones B (accL = P @ 1) on the matrix pipe.
// Final form: R10/R11/R13/R15/R17/R18/R22 variants all measured slower.
__global__ __launch_bounds__(256, 6)
void attn_kernel(const bf16_t* __restrict__ qh, const bf16_t* __restrict__ kh,
                 const bf16_t* __restrict__ vT, bf16_t* __restrict__ O)
{
    __shared__ bf16x8 lK[64 * 8];      // [krow][dh-chunk], swizzled, 8 KB
    __shared__ bf16x8 lV[64 * 8];      // [dh][kcol-chunk], swizzled, 8 KB
    __shared__ bf16x8 lP8[4][128];     // per-wave P tile [16 q][64 kv], swizzled, 8 KB
    const int tid = threadIdx.x, wid = tid >> 6, lane = tid & 63;
    const int lr = lane & 15, lh = lane >> 4;
    const int bh = blockIdx.x & 63;          // bh%8 = xcd: q-slices of one bh share XCD
    const int t  = 31 - (blockIdx.x >> 6);   // 31..0, largest work first
    const bf16_t* Qp = qh + (size_t)bh * S_ * DH_;
    const bf16_t* Kp = kh + (size_t)bh * S_ * DH_;
    const bf16_t* Vp = vT + (size_t)bh * DH_ * S_;
    char* lP = (char*)lP8[wid];
    const int b = bh >> 4, h = bh & 15;
    const float QSCALE = 0.125f * 1.44269504f;   // 1/sqrt(DH) * log2(e)
    const int wq = t * 64 + wid * 16;
    const bf16x8 ones8 = { (__bf16)1.f, (__bf16)1.f, (__bf16)1.f, (__bf16)1.f,
                           (__bf16)1.f, (__bf16)1.f, (__bf16)1.f, (__bf16)1.f };

    // Q fragments (B-operand of S^T), pre-scaled into log2 domain
    bf16x8 qf[2];
    #pragma unroll
    for (int ks = 0; ks < 2; ++ks) {
        bf16x8 q8 = *(const bf16x8*)(Qp + (size_t)(wq + lr) * DH_ + ks * 32 + lh * 8);
        #pragma unroll
        for (int e = 0; e < 8; ++e) q8[e] = (__bf16)((float)q8[e] * QSCALE);
        qf[ks] = q8;
    }

    f32x4 accO[4] = {};
    f32x4 accL = {};                   // MFMA-accumulated row sums (all cols equal)
    float mrun = -1e30f;
    const int nkt = t + 1;

    #pragma unroll 1
    for (int kt = 0; kt < nkt; ++kt) {
        __syncthreads();
        #pragma unroll
        for (int i = 0; i < 2; ++i) {    // K/V staging: 512 slots each, 4 waves x 2 iters
            int base = i * 256 + (wid << 6);
            int slot = base + lane;
            int row = slot >> 3, s = slot & 7, c = s ^ (row & 7);
            glds16(Kp + (size_t)(kt * 64 + row) * DH_ + c * 8, &lK[base]);
            glds16(Vp + (size_t)row * S_ + kt * 64 + c * 8, &lV[base]);
        }
        __syncthreads();

        // S^T = K.Q^T : sc[kvi], kv row = 16*kvi + 4*lh + j, q col = lr
        f32x4 sc[4] = {};
        __builtin_amdgcn_s_setprio(1);
        #pragma unroll
        for (int ks = 0; ks < 2; ++ks) {
            int kh8 = ks * 4 + lh;
            #pragma unroll
            for (int kvi = 0; kvi < 4; ++kvi) {
                int r = kvi * 16 + lr;
                bf16x8 kf = lK[r * 8 + (kh8 ^ (r & 7))];
                sc[kvi] = mfma16(kf, qf[ks], sc[kvi]);
            }
        }
        __builtin_amdgcn_s_setprio(0);

        const int kvb = kt * 64 + 4 * lh;
        const int qg = wq + lr;
        float pv[16];
        if (kt == t) {                       // diagonal tile: causal mask (uniform branch)
            #pragma unroll
            for (int kvi = 0; kvi < 4; ++kvi)
                #pragma unroll
                for (int j = 0; j < 4; ++j) {
                    float x = sc[kvi][j];
                    if ((kvb + kvi * 16 + j) > qg) x = -1e30f;
                    pv[kvi * 4 + j] = x;
                }
        } else {
            #pragma unroll
            for (int kvi = 0; kvi < 4; ++kvi)
                #pragma unroll
                for (int j = 0; j < 4; ++j) pv[kvi * 4 + j] = sc[kvi][j];
        }

        // partial (per-lane) max via max3 triples: 8 ops
        float t0 = fmaxf(fmaxf(pv[0],  pv[1]),  pv[2]);
        float t1 = fmaxf(fmaxf(pv[3],  pv[4]),  pv[5]);
        float t2 = fmaxf(fmaxf(pv[6],  pv[7]),  pv[8]);
        float t3 = fmaxf(fmaxf(pv[9],  pv[10]), pv[11]);
        float t4 = fmaxf(fmaxf(pv[12], pv[13]), pv[14]);
        float u0 = fmaxf(fmaxf(t0, t1), t2);
        float u1 = fmaxf(fmaxf(t3, t4), pv[15]);
        float mxp = fmaxf(u0, u1);           // partial max (this lane only)

        float mnew = mrun;
        bool skip = __all(mxp <= mrun + 8.0f);   // defer-max: P bounded by 2^8
        if (!skip) {
            float mx = fmaxf(mxp, __shfl_xor(mxp, 16));   // full row max (rare path)
            mx = fmaxf(mx, __shfl_xor(mx, 32));
            mnew = fmaxf(mrun, mx);
            float rs = fast_exp2(mrun - mnew);
            mrun = mnew;
            #pragma unroll
            for (int j = 0; j < 4; ++j) {
                float rj = __shfl(rs, 4 * lh + j);
                #pragma unroll
                for (int ni = 0; ni < 4; ++ni) accO[ni][j] *= rj;
                accL[j] *= rj;
            }
        }
        // exp2 (no cross-lane, no explicit sum — MFMA handles it)
        #pragma unroll
        for (int i = 0; i < 16; ++i) pv[i] = fast_exp2(pv[i] - mnew);

        // write P[q][kv] to per-wave LDS: 8B per kvi, 16B-slot XOR swizzle
        #pragma unroll
        for (int kvi = 0; kvi < 4; ++kvi) {
            bf16x4 hv = { (__bf16)pv[kvi * 4 + 0], (__bf16)pv[kvi * 4 + 1],
                          (__bf16)pv[kvi * 4 + 2], (__bf16)pv[kvi * 4 + 3] };
            int slot = 2 * kvi + (lh >> 1);
            *(bf16x4*)(lP + lr * 128 + ((slot ^ (lr & 7)) * 16) + (lh & 1) * 8) = hv;
        }

        // PV: O += P @ V  and  L += P @ 1  (A = P from per-wave LDS)
        __builtin_amdgcn_s_setprio(1);
        #pragma unroll
        for (int ks = 0; ks < 2; ++ks) {
            int kh8 = ks * 4 + lh;
            int slot = 4 * ks + lh;
            bf16x8 pf = *(const bf16x8*)(lP + lr * 128 + ((slot ^ (lr & 7)) * 16));
            #pragma unroll
            for (int ni = 0; ni < 4; ++ni) {
                int r = ni * 16 + lr;
                bf16x8 vf = lV[r * 8 + (kh8 ^ (r & 7))];
                accO[ni] = mfma16(pf, vf, accO[ni]);
            }
            accL = mfma16(pf, ones8, accL);   // row sums (denominator), matrix pipe
        }
        __builtin_amdgcn_s_setprio(0);
    }

    // epilogue: rows q = 4*lh + j, col dh = ni*16 + lr; accL[j] = row sum (all lanes)
    #pragma unroll
    for (int j = 0; j < 4; ++j) {
        int s = wq + 4 * lh + j;
        float inv = 1.f / accL[j];
        #pragma unroll
        for (int ni = 0; ni < 4; ++ni) {
            int dh = ni * 16 + lr;
            O[((size_t)(b * S_ + s)) * D_ + h * DH_ + dh] = (bf16_t)(accO[ni][j] * inv);
        }
    }
}

// ---------------- Output GEMM: 2-phase double-buffered, glds both sides -------------
__global__ __launch_bounds__(256)
void out_kernel(const bf16_t* __restrict__ A, const bf16_t* __restrict__ W,
                float* __restrict__ out)
{
    __shared__ bf16x8 lA[2][128 * 8];   // 32 KB
    __shared__ bf16x8 lB[2][128 * 8];   // 32 KB
    const int tid = threadIdx.x;
    const int gm0 = blockIdx.x * 128;
    const int gn0 = blockIdx.y * 128;
    const int wid = tid >> 6, lane = tid & 63;
    const int lr = lane & 15, lh = lane >> 4;
    const int wm = (wid >> 1) * 64, wn = (wid & 1) * 64;

    const bf16_t* asrc[4]; const bf16_t* bsrc[4]; int sbase[4];
    #pragma unroll
    for (int i = 0; i < 4; ++i) {
        int base = wid * 64 + i * 256;
        int slot = base + lane;
        int row = slot >> 3, s = slot & 7, c = s ^ (row & 7);
        sbase[i] = base;
        asrc[i] = A + (size_t)(gm0 + row) * D_ + c * 8;
        bsrc[i] = W + (size_t)(gn0 + row) * D_ + c * 8;
    }

    // prologue: stage tile 0
    #pragma unroll
    for (int i = 0; i < 4; ++i) {
        glds16(asrc[i], &lA[0][sbase[i]]);
        glds16(bsrc[i], &lB[0][sbase[i]]);
    }
    __syncthreads();

    f32x4 acc[4][4] = {};
    int cur = 0;

    #pragma unroll 1
    for (int kt = 0; kt < D_ / 64; ++kt) {
        const int nxt = cur ^ 1;
        if (kt + 1 < D_ / 64) {
            #pragma unroll
            for (int i = 0; i < 4; ++i) {
                glds16(asrc[i] + (kt + 1) * 64, &lA[nxt][sbase[i]]);
                glds16(bsrc[i] + (kt + 1) * 64, &lB[nxt][sbase[i]]);
            }
        }
        #pragma unroll
        for (int ks = 0; ks < 2; ++ks) {
            bf16x8 af[4], bfr[4];
            int kh = ks * 4 + lh;
            #pragma unroll
            for (int mi = 0; mi < 4; ++mi) { int r = wm + mi * 16 + lr; af[mi]  = lA[cur][r * 8 + (kh ^ (r & 7))]; }
            #pragma unroll
            for (int ni = 0; ni < 4; ++ni) { int r = wn + ni * 16 + lr; bfr[ni] = lB[cur][r * 8 + (kh ^ (r & 7))]; }
            #pragma unroll
            for (int mi = 0; mi < 4; ++mi)
                #pragma unroll
                for (int ni = 0; ni < 4; ++ni)
                    acc[mi][ni] = mfma16(af[mi], bfr[ni], acc[mi][ni]);
        }
        __syncthreads();     // single barrier: drains next-tile glds
        cur = nxt;
    }

    #pragma unroll
    for (int mi = 0; mi < 4; ++mi)
        #pragma unroll
        for (int j = 0; j < 4; ++j) {
            int m = gm0 + wm + mi * 16 + lh * 4 + j;
            #pragma unroll
            for (int ni = 0; ni < 4; ++ni) {
                int n = gn0 + wn + ni * 16 + lr;
                out[(size_t)m * D_ + n] = acc[mi][ni][j];
            }
        }
}

extern "C" void kernel_launch(void* const* d_in, const int* in_sizes, int n_in,
                              void* d_out, int out_size, void* d_ws, size_t ws_size,
                              hipStream_t stream)
{
    const float* Q  = (const float*)d_in[0];
    const float* K  = (const float*)d_in[1];
    const float* V  = (const float*)d_in[2];
    const float* Wq = (const float*)d_in[3];
    const float* Wk = (const float*)d_in[4];
    const float* Wv = (const float*)d_in[5];
    const float* Wo = (const float*)d_in[6];
    float* out = (float*)d_out;

    char* ws = (char*)d_ws;
    const size_t MB = 1024 * 1024;
    bf16_t* qh  = (bf16_t*)(ws);                // [B][H][S][DH] bf16, 16 MB
    bf16_t* khb = (bf16_t*)(ws + 16 * MB);      // [B][H][S][DH] bf16, 16 MB
    bf16_t* vT  = (bf16_t*)(ws + 32 * MB);      // [B][H][DH][S] bf16, 16 MB
    bf16_t* Ob  = (bf16_t*)(ws + 48 * MB);      // [B*S][D] bf16, 16 MB
    bf16_t* Wb  = (bf16_t*)(ws + 64 * MB);      // 4 x [1024*1024] bf16, 8 MB
    float2* tab = (float2*)(ws + 72 * MB);      // [S][32] (sin,cos), 512 KB

    prep_kernel<<<2304, 256, 0, stream>>>(Wq, Wk, Wv, Wo, Wb, tab);

    dim3 g(64, 8);
    proj_kernel<0><<<g, 256, 0, stream>>>(Q, Wb + 0 * 1048576, qh, tab);
    proj_kernel<0><<<g, 256, 0, stream>>>(K, Wb + 1 * 1048576, khb, tab);
    proj_kernel<1><<<g, 256, 0, stream>>>(V, Wb + 2 * 1048576, vT, tab);

    attn_kernel<<<2048, 256, 0, stream>>>(qh, khb, vT, Ob);

    out_kernel<<<dim3(64, 8), 256, 0, stream>>>(Ob, Wb + 3 * 1048576, out);
}